// Round 5
// baseline (161.751 us; speedup 1.0000x reference)
//
#include <hip/hip_runtime.h>
#include <math.h>

#define NN 4096
#define F_IN 512
#define HEADS 8
#define D_HEAD 8
#define C1 64
#define NCLASS 16
#define MAX_DEG 128
#define LEAKY 0.2f

// ---------------- Kernel W: transpose W1[h][f][d] -> Wt[c][f], c=h*8+d ----------------
__global__ __launch_bounds__(256) void k_wt(const float* __restrict__ W1,
                                            float* __restrict__ Wt) {
    const int i = blockIdx.x * 256 + threadIdx.x;  // 32 blocks -> 8192 threads
#pragma unroll
    for (int r = 0; r < 4; r++) {
        int o = r * 8192 + i;          // output index, coalesced writes
        int c = o >> 9, f = o & 511;
        int h = c >> 3, d = c & 7;
        Wt[o] = W1[(h << 12) | (f << 3) | d];
    }
}

// ---------------- Kernel A: h1 = x @ W1, fused e_src/e_dst dots ----------------
// 512 blocks x 256 thr; block = 8 rows; wave wv handles rows n0+2wv, n0+2wv+1; lane c = channel
__global__ __launch_bounds__(256) void k_proj1(const float* __restrict__ x,
                                               const float* __restrict__ Wt,
                                               const float* __restrict__ a1s,
                                               const float* __restrict__ a1d,
                                               float* __restrict__ h1,
                                               float* __restrict__ es1,
                                               float* __restrict__ ed1) {
    __shared__ float xs[8 * F_IN];  // 16 KB
    const int t = threadIdx.x;
    const int n0 = blockIdx.x * 8;
    const float4* x4 = (const float4*)(x + (size_t)n0 * F_IN);
    float4* xs4 = (float4*)xs;
#pragma unroll
    for (int i = 0; i < 4; i++) xs4[t + i * 256] = x4[t + i * 256];
    __syncthreads();

    const int c = t & 63;
    const int wv = t >> 6;
    const float4* wrow = (const float4*)(Wt + c * F_IN);
    const float4* r0 = (const float4*)(xs + (2 * wv + 0) * F_IN);
    const float4* r1 = (const float4*)(xs + (2 * wv + 1) * F_IN);
    // 8 independent accumulator chains (4 per row)
    float ax0 = 0.f, ay0 = 0.f, az0 = 0.f, aw0 = 0.f;
    float ax1 = 0.f, ay1 = 0.f, az1 = 0.f, aw1 = 0.f;
#pragma unroll 4
    for (int q = 0; q < F_IN / 4; q++) {
        float4 w = wrow[q];
        float4 u = r0[q];
        float4 v = r1[q];
        ax0 += u.x * w.x; ay0 += u.y * w.y; az0 += u.z * w.z; aw0 += u.w * w.w;
        ax1 += v.x * w.x; ay1 += v.y * w.y; az1 += v.z * w.z; aw1 += v.w * w.w;
    }
    float A = (ax0 + ay0) + (az0 + aw0);
    float B = (ax1 + ay1) + (az1 + aw1);
    const float as = a1s[c], ad = a1d[c];
    const int h = c >> 3, d = c & 7;
    float vals[2] = {A, B};
#pragma unroll
    for (int q = 0; q < 2; q++) {
        int n = n0 + 2 * wv + q;
        float v = vals[q];
        h1[(size_t)n * C1 + c] = v;
        float vs = v * as, vd = v * ad;
        vs += __shfl_xor(vs, 1, 64); vd += __shfl_xor(vd, 1, 64);
        vs += __shfl_xor(vs, 2, 64); vd += __shfl_xor(vd, 2, 64);
        vs += __shfl_xor(vs, 4, 64); vd += __shfl_xor(vd, 4, 64);
        if (d == 0) { es1[n * HEADS + h] = vs; ed1[n * HEADS + h] = vd; }
    }
}

// ---------------- Kernel B: build CSR from dense adj (read adj exactly once) ----------------
__global__ __launch_bounds__(256) void k_csr(const float* __restrict__ adj,
                                             int* __restrict__ deg,
                                             int* __restrict__ cols) {
    __shared__ int cnt;
    __shared__ int cls[MAX_DEG];
    const int n = blockIdx.x, t = threadIdx.x;
    if (t == 0) cnt = 0;
    __syncthreads();
    const float4* row4 = (const float4*)(adj + (size_t)n * NN);
#pragma unroll
    for (int i = 0; i < 4; i++) {
        float4 v = row4[i * 256 + t];
        int base = (i * 256 + t) * 4;
        if (v.x > 0.f) { int p = atomicAdd(&cnt, 1); if (p < MAX_DEG) cls[p] = base; }
        if (v.y > 0.f) { int p = atomicAdd(&cnt, 1); if (p < MAX_DEG) cls[p] = base + 1; }
        if (v.z > 0.f) { int p = atomicAdd(&cnt, 1); if (p < MAX_DEG) cls[p] = base + 2; }
        if (v.w > 0.f) { int p = atomicAdd(&cnt, 1); if (p < MAX_DEG) cls[p] = base + 3; }
    }
    __syncthreads();
    int dc = cnt < MAX_DEG ? cnt : MAX_DEG;
    if (t == 0) deg[n] = dc;
    for (int i = t; i < dc; i += 256) cols[n * MAX_DEG + i] = cls[i];
}

// ---------------- Kernel C: layer-1 attn+aggregate (4 waves/node), ELU, W2 proj, e2 dots ----
__global__ __launch_bounds__(256) void k_layer1(const float* __restrict__ h1,
                                                const float* __restrict__ es1,
                                                const float* __restrict__ ed1,
                                                const int* __restrict__ deg,
                                                const int* __restrict__ cols,
                                                const float* __restrict__ W2,
                                                const float* __restrict__ a2s,
                                                const float* __restrict__ a2d,
                                                float* __restrict__ h2,
                                                float* __restrict__ es2,
                                                float* __restrict__ ed2) {
    __shared__ int cls[MAX_DEG];
    __shared__ float pM[4][C1], pS[4][C1], pA[4][C1];
    __shared__ float row[C1];
    const int n = blockIdx.x, t = threadIdx.x;
    const int wv = t >> 6, ln = t & 63;
    const int dg = deg[n];
    for (int i = t; i < dg; i += 256) cls[i] = cols[n * MAX_DEG + i];
    __syncthreads();
    const int h = ln >> 3;
    const float es = es1[n * HEADS + h];
    float M = -1e30f, S = 0.f, acc = 0.f;
    for (int j = wv; j < dg; j += 4) {
        int m = cls[j];
        float e = es + ed1[m * HEADS + h];
        e = e > 0.f ? e : LEAKY * e;
        float hv = h1[(size_t)m * C1 + ln];
        float Mn = fmaxf(M, e);
        float sc = __expf(M - Mn);
        float p = __expf(e - Mn);
        acc = acc * sc + p * hv;
        S = S * sc + p;
        M = Mn;
    }
    pM[wv][ln] = M; pS[wv][ln] = S; pA[wv][ln] = acc;
    __syncthreads();
    if (wv == 0) {
#pragma unroll
        for (int q = 1; q < 4; q++) {
            float Mo = pM[q][ln], So = pS[q][ln], ao = pA[q][ln];
            float Mn = fmaxf(M, Mo);
            float s1 = __expf(M - Mn), s2 = __expf(Mo - Mn);
            acc = acc * s1 + ao * s2;
            S = S * s1 + So * s2;
            M = Mn;
        }
        float o = acc / S;
        o = o > 0.f ? o : __expf(o) - 1.f;  // ELU
        row[ln] = o;
    }
    __syncthreads();
    if (wv == 0) {
        const int k = ln & 15, g = ln >> 4;
        float hk = 0.f;
#pragma unroll
        for (int cc = 0; cc < 16; cc++) {
            int c2 = g * 16 + cc;
            hk += row[c2] * W2[c2 * NCLASS + k];
        }
        hk += __shfl_xor(hk, 16, 64);
        hk += __shfl_xor(hk, 32, 64);
        if (ln < 16) h2[n * NCLASS + k] = hk;
        float vs = hk * a2s[k];
        float vd = hk * a2d[k];
#pragma unroll
        for (int msk = 8; msk >= 1; msk >>= 1) {
            vs += __shfl_xor(vs, msk, 64);
            vd += __shfl_xor(vd, msk, 64);
        }
        if (ln == 0) { es2[n] = vs; ed2[n] = vd; }
    }
}

// ---------------- Kernel D: layer-2 attention+aggregate + log_softmax ----------------
__global__ __launch_bounds__(64) void k_layer2(const float* __restrict__ h2,
                                               const float* __restrict__ es2,
                                               const float* __restrict__ ed2,
                                               const int* __restrict__ deg,
                                               const int* __restrict__ cols,
                                               float* __restrict__ out) {
    __shared__ int cls[MAX_DEG];
    const int n = blockIdx.x, t = threadIdx.x;
    const int dg = deg[n];
    for (int i = t; i < dg; i += 64) cls[i] = cols[n * MAX_DEG + i];
    __syncthreads();
    const int k = t & 15, g = t >> 4;
    const float es = es2[n];
    float M = -1e30f, S = 0.f, acc = 0.f;
    for (int j = g; j < dg; j += 4) {
        int m = cls[j];
        float e = es + ed2[m];
        e = e > 0.f ? e : LEAKY * e;
        float hv = h2[m * NCLASS + k];
        float Mn = fmaxf(M, e);
        float sc = __expf(M - Mn);
        float p = __expf(e - Mn);
        acc = acc * sc + p * hv;
        S = S * sc + p;
        M = Mn;
    }
#pragma unroll
    for (int msk = 16; msk <= 32; msk <<= 1) {
        float Mo = __shfl_xor(M, msk, 64);
        float So = __shfl_xor(S, msk, 64);
        float ao = __shfl_xor(acc, msk, 64);
        float Mn = fmaxf(M, Mo);
        float s1 = __expf(M - Mn), s2 = __expf(Mo - Mn);
        acc = acc * s1 + ao * s2;
        S = S * s1 + So * s2;
        M = Mn;
    }
    float v = acc / S;
    float mx = v;
#pragma unroll
    for (int msk = 1; msk <= 8; msk <<= 1) mx = fmaxf(mx, __shfl_xor(mx, msk, 64));
    float ex = __expf(v - mx);
    float se = ex;
#pragma unroll
    for (int msk = 1; msk <= 8; msk <<= 1) se += __shfl_xor(se, msk, 64);
    float r = v - mx - __logf(se);
    if (t < 16) out[n * NCLASS + k] = r;
}

extern "C" void kernel_launch(void* const* d_in, const int* in_sizes, int n_in,
                              void* d_out, int out_size, void* d_ws, size_t ws_size,
                              hipStream_t stream) {
    const float* x   = (const float*)d_in[0];
    const float* adj = (const float*)d_in[1];
    const float* W1  = (const float*)d_in[2];
    const float* a1s = (const float*)d_in[3];
    const float* a1d = (const float*)d_in[4];
    const float* W2  = (const float*)d_in[5];
    const float* a2s = (const float*)d_in[6];
    const float* a2d = (const float*)d_in[7];
    float* out = (float*)d_out;

    float* ws  = (float*)d_ws;
    float* h1  = ws;                  // 4096*64
    float* es1 = h1 + NN * C1;        // 4096*8
    float* ed1 = es1 + NN * HEADS;    // 4096*8
    float* h2  = ed1 + NN * HEADS;    // 4096*16
    float* es2 = h2 + NN * NCLASS;    // 4096
    float* ed2 = es2 + NN;            // 4096
    int* deg  = (int*)(ed2 + NN);     // 4096
    int* cols = deg + NN;             // 4096*MAX_DEG
    float* Wt = (float*)(cols + NN * MAX_DEG);  // 64*512

    k_wt<<<32, 256, 0, stream>>>(W1, Wt);
    k_csr<<<NN, 256, 0, stream>>>(adj, deg, cols);
    k_proj1<<<NN / 8, 256, 0, stream>>>(x, Wt, a1s, a1d, h1, es1, ed1);
    k_layer1<<<NN, 256, 0, stream>>>(h1, es1, ed1, deg, cols, W2, a2s, a2d, h2, es2, ed2);
    k_layer2<<<NN, 64, 0, stream>>>(h2, es2, ed2, deg, cols, out);
}